// Round 2
// baseline (361.196 us; speedup 1.0000x reference)
//
#include <hip/hip_runtime.h>

#define NB 512
#define NPG 256
#define NTOT (NB * NPG)
#define NEGMIN -3.4028234663852886e38f

// workspace layout (float offsets)
#define OFF_WNT 0       // WnT[64][16]   WnT[d][k] = Wn[k][d]
#define OFF_WCT 1024    // WcT[64][64]   WcT[d][k] = Wc[k][d]
#define OFF_W1AT 5120   // W1aT[128][64] W1aT[j][k] = W1[k][j]      (rows 0..63 of W1)
#define OFF_W1BT 13312  // W1bT[128][64] W1bT[j][k] = W1[64+k][j]   (rows 64..127)
#define OFF_BNC 21504   // bn + bc [64]
#define WS_FLOATS 21568

__global__ __launch_bounds__(256) void prep_kernel(
    const float* __restrict__ Wn, const float* __restrict__ bn,
    const float* __restrict__ Wc, const float* __restrict__ bc,
    const float* __restrict__ W1, float* __restrict__ ws)
{
    int i = blockIdx.x * 256 + threadIdx.x;
    if (i < 1024) {
        int d = i >> 4, k = i & 15;
        ws[OFF_WNT + i] = Wn[k * 64 + d];
    } else if (i < 5120) {
        int j = i - 1024; int d = j >> 6, k = j & 63;
        ws[OFF_WCT + j] = Wc[k * 64 + d];
    } else if (i < 13312) {
        int j = i - 5120; int r = j >> 6, k = j & 63;
        ws[OFF_W1AT + j] = W1[k * 128 + r];
    } else if (i < 21504) {
        int j = i - 13312; int r = j >> 6, k = j & 63;
        ws[OFF_W1BT + j] = W1[(64 + k) * 128 + r];
    } else if (i < WS_FLOATS) {
        int d = i - OFF_BNC;
        ws[OFF_BNC + d] = bn[d] + bc[d];
    }
}

// One block (512 threads) per graph; TWO threads per node, split by dim-half
// (H = t>>8, wave-uniform). Same 67 KB LDS as the 256-thread version but
// 16 waves/CU instead of 8 -> 4 waves/SIMD to hide LDS gather latency.
//
// Numerical exactness contract (argmax is rounding-sensitive; the passing
// round-0 kernel sat at absmax 82.0 / threshold 89.6): every float written
// here is BITWISE IDENTICAL to round-0. In particular:
//  - imc/h0: bias-init fold over k=0..15 (not sum-then-add-bias)
//  - pooled matmul: after the half-exchange through hsh, each thread reads
//    back the FULL pooled row (natural dim order) so the fold is k=0..63
//    ascending for BOTH halves (a half-swapped fold for H=1 was the R1 bug)
//  - graph-embed + 128-j MLP: exact round-0 code under if(t<256)
__global__ __launch_bounds__(512, 4) void gdqn_kernel(
    const float* __restrict__ nfg, const int* __restrict__ esrcg,
    const int* __restrict__ fmask, const float* __restrict__ ws,
    const float* __restrict__ bn, const float* __restrict__ b1,
    const float* __restrict__ W2, const float* __restrict__ b2,
    float* __restrict__ out)
{
    extern __shared__ float smem[];
    float* hsh  = smem;                     // 256*64 = 16384 (swizzled rows)
    float* part = smem + 16384;             // 256
    float* gesh = smem + 16640;             // 64
    float* rpsh = smem + 16704;             // 128
    float* redv = smem + 16832;             // 4
    int*   redi = (int*)(smem + 16836);     // 4

    const int g = blockIdx.x, t = threadIdx.x;
    const int n = t & 255;                  // node within graph
    const int H = __builtin_amdgcn_readfirstlane(t >> 8);  // wave-uniform half
    const int node = (g << 8) + n;
    const int sw = n & 7;
    float* myrow = hsh + (n << 6);

    const float* WnT  = ws + OFF_WNT;
    const float* WcT  = ws + OFF_WCT;
    const float* W1aT = ws + OFF_W1AT;
    const float* bnc  = ws + OFF_BNC;

    // node features (16 floats) -> regs (static indices only)
    float nf[16];
    {
        const float4* p = (const float4*)(nfg + node * 16);
        float4 a = p[0], b = p[1], c = p[2], d = p[3];
        nf[0]=a.x; nf[1]=a.y; nf[2]=a.z; nf[3]=a.w;
        nf[4]=b.x; nf[5]=b.y; nf[6]=b.z; nf[7]=b.w;
        nf[8]=c.x; nf[9]=c.y; nf[10]=c.z; nf[11]=c.w;
        nf[12]=d.x; nf[13]=d.y; nf[14]=d.z; nf[15]=d.w;
    }
    // neighbor indices packed 4-per-register (values < 256) -> 4 VGPRs
    int esp[4];
    {
        const int4* p = (const int4*)(esrcg + node * 16);
        int4 a = p[0], b = p[1], c = p[2], d = p[3];
        esp[0] = (a.x&255) | ((a.y&255)<<8) | ((a.z&255)<<16) | ((a.w&255)<<24);
        esp[1] = (b.x&255) | ((b.y&255)<<8) | ((b.z&255)<<16) | ((b.w&255)<<24);
        esp[2] = (c.x&255) | ((c.y&255)<<8) | ((c.z&255)<<16) | ((c.w&255)<<24);
        esp[3] = (d.x&255) | ((d.y&255)<<8) | ((d.z&255)<<16) | ((d.w&255)<<24);
    }

    // h0 = relu(bn-fold), imc = bnc-fold -- both exact round-0 sequences,
    // only for my 32 dims. Shared weight loads.
    const int dbase = H << 5;
    float imc[32];
    #pragma unroll
    for (int c = 0; c < 8; ++c) {
        float s4[4];
        #pragma unroll
        for (int q = 0; q < 4; ++q) {
            int dq = 4 * c + q, d = dbase + dq;
            float s0 = bn[d], si = bnc[d];
            #pragma unroll
            for (int k = 0; k < 16; ++k) {
                float w = WnT[d * 16 + k];
                s0 = fmaf(nf[k], w, s0);
                si = fmaf(nf[k], w, si);
            }
            imc[dq] = si;
            s4[q] = fmaxf(s0, 0.0f);
        }
        ((float4*)myrow)[((H << 3) | c) ^ sw] = make_float4(s4[0], s4[1], s4[2], s4[3]);
    }
    __syncthreads();

    const int Hb = H << 7;  // byte offset of my half within a 256 B row
    for (int lv = 0; lv < 3; ++lv) {
        // gather my k-half (8 chunks) of 16 neighbor rows; per-k fold over
        // neighbors j=0..15 ascending (exact round-0 order)
        float own[32];
        #pragma unroll
        for (int i = 0; i < 32; ++i) own[i] = 0.0f;
        const char* bp = (const char*)hsh;
        #pragma unroll
        for (int j = 0; j < 16; ++j) {
            int s = (esp[j >> 2] >> ((j & 3) * 8)) & 255;
            int vb = (s << 8) | ((s & 7) << 4) | Hb;   // swizzle folded into base
            #pragma unroll
            for (int c = 0; c < 8; ++c) {
                float4 v = *(const float4*)(bp + (vb ^ (c << 4)));
                own[4*c+0] += v.x; own[4*c+1] += v.y;
                own[4*c+2] += v.z; own[4*c+3] += v.w;
            }
        }
        __syncthreads();   // all gather reads of old h done

        // exchange: write my pooled half into my row (natural dim position)
        #pragma unroll
        for (int c = 0; c < 8; ++c)
            ((float4*)myrow)[((H << 3) | c) ^ sw] =
                make_float4(own[4*c+0], own[4*c+1], own[4*c+2], own[4*c+3]);
        __syncthreads();   // both halves of pooled[n] visible

        // read back the FULL pooled row in natural order (exact k sequence)
        float pl[64];
        #pragma unroll
        for (int c = 0; c < 16; ++c) {
            float4 v = ((const float4*)myrow)[c ^ sw];
            pl[4*c+0] = v.x; pl[4*c+1] = v.y; pl[4*c+2] = v.z; pl[4*c+3] = v.w;
        }
        __syncthreads();   // pair finished reading before h overwrite

        // h[d] = relu(imc-fold + pooled k=0..63 ascending) for my 32 dims
        #pragma unroll
        for (int c = 0; c < 8; ++c) {
            float s4[4];
            #pragma unroll
            for (int q = 0; q < 4; ++q) {
                int dq = 4 * c + q, d = dbase + dq;
                const float* wr = WcT + d * 64;
                float s = imc[dq];
                #pragma unroll
                for (int k = 0; k < 64; ++k) s = fmaf(pl[k], wr[k], s);
                s4[q] = fmaxf(s, 0.0f);
            }
            ((float4*)myrow)[((H << 3) | c) ^ sw] = make_float4(s4[0], s4[1], s4[2], s4[3]);
        }
        __syncthreads();
    }

    // graph_embed = relu(column sums of h) -- exact round-0 code (t<256)
    if (t < 256) {
        int col = t & 63, v0 = (t >> 6) << 6;
        float s = 0.0f;
        for (int v = 0; v < 64; ++v) {
            int vv = v0 + v;
            s += hsh[(vv << 6) + ((((col >> 2) ^ (vv & 7)) << 2) | (col & 3))];
        }
        part[t] = s;
    }
    __syncthreads();
    if (t < 64) {
        float s = part[t] + part[t + 64] + part[t + 128] + part[t + 192];
        gesh[t] = fmaxf(s, 0.0f);
    }
    __syncthreads();
    // rep_proj[j] = b1[j] + sum_k ge[k] * W1[64+k][j]  (block-uniform MLP half)
    if (t < 128) {
        float s = b1[t];
        const float4* wr = (const float4*)(ws + OFF_W1BT + t * 64);
        #pragma unroll
        for (int c = 0; c < 16; ++c) {
            float4 w = wr[c];
            s = fmaf(gesh[4*c+0], w.x, s);
            s = fmaf(gesh[4*c+1], w.y, s);
            s = fmaf(gesh[4*c+2], w.z, s);
            s = fmaf(gesh[4*c+3], w.w, s);
        }
        rpsh[t] = s;
    }
    __syncthreads();   // rpsh ready

    if (t < 256) {
        // reload full h row (both halves live in my row)
        float h[64];
        #pragma unroll
        for (int c = 0; c < 16; ++c) {
            float4 v = ((const float4*)myrow)[c ^ sw];
            h[4*c+0] = v.x; h[4*c+1] = v.y; h[4*c+2] = v.z; h[4*c+3] = v.w;
        }

        // raw_pred: exact round-0 fold j=0..127 from b2[0]
        float raw = b2[0];
        for (int j = 0; j < 128; ++j) {     // j wave-uniform; h[k] static
            float z = rpsh[j];
            const float* wr = W1aT + j * 64;
            #pragma unroll
            for (int k = 0; k < 64; ++k) z = fmaf(h[k], wr[k], z);
            raw = fmaf(fmaxf(z, 0.0f), W2[j], raw);
        }
        out[512 + node] = raw;

        // masked max/argmax (first-index tie-break like jnp.argmax)
        float q = fmask[node] ? NEGMIN : raw;
        int idx = t;
        #pragma unroll
        for (int off = 32; off >= 1; off >>= 1) {
            float ov = __shfl_down(q, off, 64);
            int oi  = __shfl_down(idx, off, 64);
            if (ov > q || (ov == q && oi < idx)) { q = ov; idx = oi; }
        }
        if ((t & 63) == 0) { redv[t >> 6] = q; redi[t >> 6] = idx; }
    }
    __syncthreads();
    if (t == 0) {
        float bv = redv[0]; int bi = redi[0];
        #pragma unroll
        for (int w = 1; w < 4; ++w) {
            float v = redv[w]; int iw = redi[w];
            if (v > bv || (v == bv && iw < bi)) { bv = v; bi = iw; }
        }
        out[g] = (float)bi;             // indices (as float)
        out[512 + NTOT + g] = bv;       // values
    }
}

extern "C" void kernel_launch(void* const* d_in, const int* in_sizes, int n_in,
                              void* d_out, int out_size, void* d_ws, size_t ws_size,
                              hipStream_t stream)
{
    const float* nfg   = (const float*)d_in[0];
    const int*   esrc  = (const int*)d_in[1];
    const int*   fmask = (const int*)d_in[4];
    const float* Wn = (const float*)d_in[5];
    const float* bn = (const float*)d_in[6];
    const float* Wc = (const float*)d_in[7];
    const float* bc = (const float*)d_in[8];
    const float* W1 = (const float*)d_in[9];
    const float* b1 = (const float*)d_in[10];
    const float* W2 = (const float*)d_in[11];
    const float* b2 = (const float*)d_in[12];
    float* out = (float*)d_out;
    float* ws  = (float*)d_ws;

    prep_kernel<<<(WS_FLOATS + 255) / 256, 256, 0, stream>>>(Wn, bn, Wc, bc, W1, ws);

    size_t shmem = 16840 * sizeof(float);  // 67,360 B > 64 KB default -> opt in
    hipFuncSetAttribute((const void*)gdqn_kernel,
                        hipFuncAttributeMaxDynamicSharedMemorySize, (int)shmem);
    gdqn_kernel<<<NB, 512, shmem, stream>>>(nfg, esrc, fmask, ws, bn, b1, W2, b2, out);
}